// Round 1
// baseline (738.512 us; speedup 1.0000x reference)
//
#include <hip/hip_runtime.h>
#include <math.h>

#define KS   7
#define PAD  3
#define TW   32
#define TH   32
#define HW_  (TW + KS - 1)   // 38
#define HH_  (TH + KS - 1)   // 38

struct G1 { float w[KS]; };

__global__ __launch_bounds__(256) void fill_step(
    const float* __restrict__ in, const float* __restrict__ sparse,
    float* __restrict__ out, G1 g, int H, int W)
{
    __shared__ float tin[HH_][HW_ + 2];   // 38 x 40 (pad to 40 for bank alignment)
    __shared__ float srow[HH_][TW];       // row-filtered sums
    __shared__ float crow[HH_][TW];       // row-filtered counts

    const int bx = blockIdx.x * TW;
    const int by = blockIdx.y * TH;
    const int b  = blockIdx.z;
    const size_t plane = (size_t)H * W;
    const float* __restrict__ inp = in + (size_t)b * plane;
    const float* __restrict__ sp  = sparse + (size_t)b * plane;
    float* __restrict__ op = out + (size_t)b * plane;

    const int tid = threadIdx.x;  // 0..255

    // ---- load (TH+6)x(TW+6) input tile, zero padded ----
    for (int i = tid; i < HH_ * HW_; i += 256) {
        int r = i / HW_, c = i % HW_;
        int gr = by + r - PAD, gc = bx + c - PAD;
        float v = 0.f;
        if (gr >= 0 && gr < H && gc >= 0 && gc < W) v = inp[(size_t)gr * W + gc];
        tin[r][c] = v;
    }
    __syncthreads();

    // ---- horizontal pass: 38 rows x 32 cols ----
    for (int i = tid; i < HH_ * TW; i += 256) {
        int r = i / TW, c = i % TW;
        float s = 0.f, cm = 0.f;
        #pragma unroll
        for (int k = 0; k < KS; ++k) {
            float v = tin[r][c + k];
            s  += g.w[k] * v;
            cm += (v != 0.f) ? g.w[k] : 0.f;   // conv of 0/1 mask
        }
        srow[r][c] = s;
        crow[r][c] = cm;
    }
    __syncthreads();

    // ---- vertical pass + divide + sparse pin: 32x32 outputs ----
    for (int i = tid; i < TH * TW; i += 256) {
        int r = i / TW, c = i % TW;
        float s = 0.f, cm = 0.f;
        #pragma unroll
        for (int k = 0; k < KS; ++k) {
            s  += g.w[k] * srow[r + k][c];
            cm += g.w[k] * crow[r + k][c];
        }
        int gr = by + r, gc = bx + c;
        if (gr < H && gc < W) {
            float sv  = sp[(size_t)gr * W + gc];
            float avg = (cm > 0.f) ? (s / cm) : 0.f;
            op[(size_t)gr * W + gc] = (sv != 0.f) ? sv : avg;
        }
    }
}

extern "C" void kernel_launch(void* const* d_in, const int* in_sizes, int n_in,
                              void* d_out, int out_size, void* d_ws, size_t ws_size,
                              hipStream_t stream)
{
    const float* sparse = (const float*)d_in[0];
    float* out = (float*)d_out;
    float* ws  = (float*)d_ws;

    const int H = 480, W = 640;
    const int B = in_sizes[0] / (H * W);   // 8

    // 1-D separable weights, double precision on host; outer(g,g) == reference 2-D kernel.
    G1 g;
    {
        double g1[KS], s = 0.0;
        for (int i = 0; i < KS; ++i) {
            double x = (i - (KS - 1) / 2.0) * 6.0 / (double)KS;  // n / (k/6)
            g1[i] = exp(-0.5 * x * x);
            s += g1[i];
        }
        for (int i = 0; i < KS; ++i) g.w[i] = (float)(g1[i] / s);
    }

    dim3 grid((W + TW - 1) / TW, (H + TH - 1) / TH, B);  // 20 x 15 x 8
    dim3 block(256);

    // Ping-pong: iter k output = (k odd ? d_out : ws); 50 iters -> iter 49 in d_out.
    const int ITERS = 50;
    const float* cur = sparse;
    for (int k = 0; k < ITERS; ++k) {
        float* dst = (k & 1) ? out : ws;
        fill_step<<<grid, block, 0, stream>>>(cur, sparse, dst, g, H, W);
        cur = dst;
    }
}

// Round 2
// 617.757 us; speedup vs baseline: 1.1955x; 1.1955x over previous
//
#include <hip/hip_runtime.h>
#include <math.h>

#define KS   7
#define PAD  3
#define TW   32
#define TH   32
#define HW_  (TW + KS - 1)   // 38
#define HH_  (TH + KS - 1)   // 38

struct G1 { float w[KS]; };

// ---------------- general kernel (count-conv), 1 iteration — used for iters 0,1 ----------------
__global__ __launch_bounds__(256) void fill_step(
    const float* __restrict__ in, const float* __restrict__ sparse,
    float* __restrict__ out, G1 g, int H, int W)
{
    __shared__ float tin[HH_][HW_ + 2];
    __shared__ float srow[HH_][TW];
    __shared__ float crow[HH_][TW];

    const int bx = blockIdx.x * TW;
    const int by = blockIdx.y * TH;
    const int b  = blockIdx.z;
    const size_t plane = (size_t)H * W;
    const float* __restrict__ inp = in + (size_t)b * plane;
    const float* __restrict__ sp  = sparse + (size_t)b * plane;
    float* __restrict__ op = out + (size_t)b * plane;

    const int tid = threadIdx.x;

    for (int i = tid; i < HH_ * HW_; i += 256) {
        int r = i / HW_, c = i % HW_;
        int gr = by + r - PAD, gc = bx + c - PAD;
        float v = 0.f;
        if (gr >= 0 && gr < H && gc >= 0 && gc < W) v = inp[(size_t)gr * W + gc];
        tin[r][c] = v;
    }
    __syncthreads();

    for (int i = tid; i < HH_ * TW; i += 256) {
        int r = i / TW, c = i % TW;
        float s = 0.f, cm = 0.f;
        #pragma unroll
        for (int k = 0; k < KS; ++k) {
            float v = tin[r][c + k];
            s  += g.w[k] * v;
            cm += (v != 0.f) ? g.w[k] : 0.f;
        }
        srow[r][c] = s;
        crow[r][c] = cm;
    }
    __syncthreads();

    for (int i = tid; i < TH * TW; i += 256) {
        int r = i / TW, c = i % TW;
        float s = 0.f, cm = 0.f;
        #pragma unroll
        for (int k = 0; k < KS; ++k) {
            s  += g.w[k] * srow[r + k][c];
            cm += g.w[k] * crow[r + k][c];
        }
        int gr = by + r, gc = bx + c;
        if (gr < H && gc < W) {
            float sv  = sp[(size_t)gr * W + gc];
            float avg = (cm > 0.f) ? (s / cm) : 0.f;
            op[(size_t)gr * W + gc] = (sv != 0.f) ? sv : avg;
        }
    }
}

// ---------------- dense kernel: 4 fused iterations, mask==1 assumed (iters >= 2) ----------------
// count_conv == fy(y)*fx(x) (separable border factor; ==1 interior). No divide (cached rcp).
#define NS   4            // iterations fused per launch
#define RB   (3 * NS)     // halo = 12
#define NT   (TW + 2*RB)  // 56 input tile side
#define STR  (NT + 1)     // 57 LDS row stride

__global__ __launch_bounds__(256, 4) void fill_dense4(
    const float* __restrict__ in, const float* __restrict__ sparse,
    float* __restrict__ out, G1 g, int H, int W)
{
    __shared__ float F[NT * STR];
    __shared__ float S[NT * STR];
    __shared__ float rfy[NT];
    __shared__ float rfx[NT];

    const int gx0 = blockIdx.x * TW - RB;   // tin origin (global coords)
    const int gy0 = blockIdx.y * TH - RB;
    const int b   = blockIdx.z;
    const size_t plane = (size_t)H * W;
    const float* __restrict__ inp = in + (size_t)b * plane;
    const float* __restrict__ sp  = sparse + (size_t)b * plane;
    float* __restrict__ op = out + (size_t)b * plane;

    const int tid = threadIdx.x;

    // load 56x56 tile (zero outside image)
    for (int i = tid; i < NT * NT; i += 256) {
        int r = i / NT, c = i - r * NT;
        int gr = gy0 + r, gc = gx0 + c;
        float v = 0.f;
        if (gr >= 0 && gr < H && gc >= 0 && gc < W) v = inp[(size_t)gr * W + gc];
        F[r * STR + c] = v;
    }
    // border-count reciprocal factors
    if (tid < 2 * NT) {
        bool isY = tid < NT;
        int t = isY ? tid : tid - NT;
        int coord = (isY ? gy0 : gx0) + t;
        int Dim = isY ? H : W;
        float f = 0.f;
        #pragma unroll
        for (int k = 0; k < KS; ++k) {
            int q = coord - PAD + k;
            if (q >= 0 && q < Dim) f += g.w[k];
        }
        float rf = (f > 0.f) ? 1.f / f : 0.f;
        if (isY) rfy[t] = rf; else rfx[t] = rf;
    }
    __syncthreads();

    #pragma unroll
    for (int j = 0; j < NS; ++j) {
        const int a  = 3 * j;            // valid F region starts
        const int hs = NT - 6 * j;       // h-pass rows
        const int cs = NT - 6 * j - 6;   // h-pass cols == emission side m

        // horizontal pass: S[u][v] = sum_k g[k]*F[u][v-3+k]
        for (int i = tid; i < hs * cs; i += 256) {
            int u = a + i / cs;
            int v = a + PAD + i - (i / cs) * cs;
            const float* fr = &F[u * STR + v - PAD];
            float s = 0.f;
            #pragma unroll
            for (int k = 0; k < KS; ++k) s += g.w[k] * fr[k];
            S[u * STR + v] = s;
        }
        __syncthreads();

        // vertical pass + border factor + pin, 4-row register blocking
        const int m  = cs;
        const int bo = a + PAD;          // emission region start
        const int ng = (m + 3) / 4;
        for (int i = tid; i < ng * m; i += 256) {
            int gi = i / m;
            int v  = bo + (i - gi * m);
            int u0 = bo + gi * 4;
            float sv[10];
            #pragma unroll
            for (int t = 0; t < 10; ++t) {
                int rr = u0 - PAD + t;
                if (rr > NT - 1) rr = NT - 1;   // clamp (partial last group; values unused)
                sv[t] = S[rr * STR + v];
            }
            float rx = rfx[v];
            #pragma unroll
            for (int t = 0; t < 4; ++t) {
                int u = u0 + t;
                if (u < bo + m) {
                    float acc = 0.f;
                    #pragma unroll
                    for (int k = 0; k < KS; ++k) acc += g.w[k] * sv[t + k];
                    int gy = gy0 + u, gx = gx0 + v;
                    float val = 0.f;
                    if (gy >= 0 && gy < H && gx >= 0 && gx < W) {
                        float spv = sp[(size_t)gy * W + gx];
                        val = (spv != 0.f) ? spv : acc * rfy[u] * rx;
                        if (j == NS - 1) op[(size_t)gy * W + gx] = val;
                    }
                    if (j != NS - 1) F[u * STR + v] = val;
                }
            }
        }
        if (j != NS - 1) __syncthreads();
    }
}

extern "C" void kernel_launch(void* const* d_in, const int* in_sizes, int n_in,
                              void* d_out, int out_size, void* d_ws, size_t ws_size,
                              hipStream_t stream)
{
    const float* sparse = (const float*)d_in[0];
    float* out = (float*)d_out;
    float* ws  = (float*)d_ws;

    const int H = 480, W = 640;
    const int B = in_sizes[0] / (H * W);

    G1 g;
    {
        double g1[KS], s = 0.0;
        for (int i = 0; i < KS; ++i) {
            double x = (i - (KS - 1) / 2.0) * 6.0 / (double)KS;
            g1[i] = exp(-0.5 * x * x);
            s += g1[i];
        }
        for (int i = 0; i < KS; ++i) g.w[i] = (float)(g1[i] / s);
    }

    dim3 grid((W + TW - 1) / TW, (H + TH - 1) / TH, B);  // 20 x 15 x 8
    dim3 block(256);

    // iters 0,1: general (count-conv). Input still ~30% dense.
    fill_step<<<grid, block, 0, stream>>>(sparse, sparse, ws, g, H, W);
    fill_step<<<grid, block, 0, stream>>>(ws, sparse, out, g, H, W);

    // iters 2..49: dense path, 4 iterations per launch, 12 launches.
    const float* cur = out;
    for (int l = 0; l < 12; ++l) {
        float* dst = (l & 1) ? out : ws;
        fill_dense4<<<grid, block, 0, stream>>>(cur, sparse, dst, g, H, W);
        cur = dst;
    }
}

// Round 4
// 513.507 us; speedup vs baseline: 1.4382x; 1.2030x over previous
//
#include <hip/hip_runtime.h>
#include <math.h>

#define KS  7
#define PAD 3

struct G1 { float w[KS]; };

// ================= general kernel (count-conv), 1 iteration — iters 0,1 =================
#define GTW 32
#define GTH 32
#define GHW (GTW + KS - 1)   // 38
#define GHH (GTH + KS - 1)   // 38

__global__ __launch_bounds__(256) void fill_step(
    const float* __restrict__ in, const float* __restrict__ sparse,
    float* __restrict__ out, G1 g, int H, int W)
{
    __shared__ float tin[GHH][GHW + 2];
    __shared__ float srow[GHH][GTW];
    __shared__ float crow[GHH][GTW];

    const int bx = blockIdx.x * GTW;
    const int by = blockIdx.y * GTH;
    const int b  = blockIdx.z;
    const size_t plane = (size_t)H * W;
    const float* __restrict__ inp = in + (size_t)b * plane;
    const float* __restrict__ sp  = sparse + (size_t)b * plane;
    float* __restrict__ op = out + (size_t)b * plane;

    const int tid = threadIdx.x;

    for (int i = tid; i < GHH * GHW; i += 256) {
        int r = i / GHW, c = i % GHW;
        int gr = by + r - PAD, gc = bx + c - PAD;
        float v = 0.f;
        if (gr >= 0 && gr < H && gc >= 0 && gc < W) v = inp[(size_t)gr * W + gc];
        tin[r][c] = v;
    }
    __syncthreads();

    for (int i = tid; i < GHH * GTW; i += 256) {
        int r = i / GTW, c = i % GTW;
        float s = 0.f, cm = 0.f;
        #pragma unroll
        for (int k = 0; k < KS; ++k) {
            float v = tin[r][c + k];
            s  += g.w[k] * v;
            cm += (v != 0.f) ? g.w[k] : 0.f;
        }
        srow[r][c] = s;
        crow[r][c] = cm;
    }
    __syncthreads();

    for (int i = tid; i < GTH * GTW; i += 256) {
        int r = i / GTW, c = i % GTW;
        float s = 0.f, cm = 0.f;
        #pragma unroll
        for (int k = 0; k < KS; ++k) {
            s  += g.w[k] * srow[r + k][c];
            cm += g.w[k] * crow[r + k][c];
        }
        int gr = by + r, gc = bx + c;
        if (gr < H && gc < W) {
            float sv  = sp[(size_t)gr * W + gc];
            float avg = (cm > 0.f) ? (s / cm) : 0.f;
            op[(size_t)gr * W + gc] = (sv != 0.f) ? sv : avg;
        }
    }
}

// ================= dense kernel: 4 fused iterations, mask==1 (iters >= 2) =================
// Uniform full-region passes; all LDS access is aligned float4. Cells outside the
// shrinking valid region compute garbage that is provably never consumed by valid outputs.
#define TW   64
#define TH   32
#define NS   4
#define HALO 12              // 3*NS
#define DW   (TW + 2*HALO)   // 88 data cols
#define DH   (TH + 2*HALO)   // 56 rows
#define LP   4               // left zero-pad cols (phys col = logical + LP)
#define SW   (LP + DW)       // 92 floats row stride (368 B, 16B-aligned rows)
#define NC4  (DW / 4)        // 22 float4 col-groups
#define NH8  11              // h-pass col groups of 8 (8*11 = 88)
#define NVS  7               // v-pass row groups of 8 (covers rows 3..52)

// Border-count reciprocal, MASKED to zero outside the image.
// CRITICAL: returning 0 outside [0,D) forces out-of-image F cells to 0 each
// iteration (reference zero-padding). Without it, fringe cells (|c| within 3
// of the border) get acc*rf with rf up to ~226 (corners ~5e4): geometric
// blow-up across iterations/launches -> Inf -> Inf*0 = NaN (the R3 failure).
__device__ __forceinline__ float rf1(int c, int D, const G1& g) {
    if (c < 0 || c >= D) return 0.f;
    float f = 0.f;
    #pragma unroll
    for (int k = 0; k < KS; ++k) {
        int q = c - PAD + k;
        if (q >= 0 && q < D) f += g.w[k];
    }
    return (f > 0.f) ? (1.f / f) : 0.f;
}

__global__ __launch_bounds__(256, 3) void fill_dense4(
    const float* __restrict__ in, const float* __restrict__ sparse,
    float* __restrict__ out, G1 g, int H, int W)
{
    // [ F: DH*SW | slack: 4 (zero) | S: DH*SW ]
    __shared__ __align__(16) float lds[DH * SW + 4 + DH * SW];
    float* Fs = lds;
    float* Ss = lds + DH * SW + 4;

    const int tid = threadIdx.x;
    const int gx0 = blockIdx.x * TW - HALO;
    const int gy0 = blockIdx.y * TH - HALO;
    const size_t plane = (size_t)H * W;
    const float* __restrict__ inp = in + (size_t)blockIdx.z * plane;
    const float* __restrict__ sp  = sparse + (size_t)blockIdx.z * plane;
    float* __restrict__ op = out + (size_t)blockIdx.z * plane;

    // zero left-pad cols + slack (read by h-pass row-wrap; must be finite)
    if (tid < DH) *(float4*)&Fs[tid * SW] = make_float4(0.f, 0.f, 0.f, 0.f);
    if (tid == 0) *(float4*)&lds[DH * SW] = make_float4(0.f, 0.f, 0.f, 0.f);

    // ---- load 56x88 tile as float4 (W,H multiples of 4 -> never partial) ----
    for (int i = tid; i < DH * NC4; i += 256) {
        int r = i / NC4, t = i - r * NC4;
        int gy = gy0 + r, gx = gx0 + 4 * t;
        float4 v = make_float4(0.f, 0.f, 0.f, 0.f);
        if (gy >= 0 && gy < H && gx >= 0 && gx < W)
            v = *(const float4*)&inp[(size_t)gy * W + gx];
        *(float4*)&Fs[r * SW + LP + 4 * t] = v;
    }

    // ---- v-item setup: fixed across iterations; sp + border factors in registers ----
    const bool vact = tid < NVS * NC4;            // 154 items
    const int  vs = tid / NC4;
    const int  vt = tid - vs * NC4;
    int u0 = 3 + 8 * vs; if (u0 > 45) u0 = 45;    // last group overlaps (benign dup)
    const int vgx = gx0 + 4 * vt;                 // logical col 4*vt
    float4 spv[8];
    float  rfy[8];
    float4 rfx = make_float4(1.f, 1.f, 1.f, 1.f);
    if (vact) {
        #pragma unroll
        for (int q = 0; q < 8; ++q) {
            int gy = gy0 + u0 + q;
            spv[q] = make_float4(0.f, 0.f, 0.f, 0.f);
            if (gy >= 0 && gy < H && vgx >= 0 && vgx < W)
                spv[q] = *(const float4*)&sp[(size_t)gy * W + vgx];
            rfy[q] = rf1(gy, H, g);               // 0 when gy outside image
        }
        rfx = make_float4(rf1(vgx, W, g), rf1(vgx + 1, W, g),
                          rf1(vgx + 2, W, g), rf1(vgx + 3, W, g));  // 0 outside
    }
    __syncthreads();

    #pragma unroll
    for (int j = 0; j < NS; ++j) {
        // ---- h-pass: 56 rows x 11 groups of 8 cols, all-aligned b128 ----
        for (int i = tid; i < DH * NH8; i += 256) {
            int r = i / NH8, t = i - (i / NH8) * NH8;
            const float* fr = &Fs[r * SW + 8 * t];           // phys 8t (16B aligned)
            float4 fa = *(const float4*)(fr);
            float4 fb = *(const float4*)(fr + 4);
            float4 fc = *(const float4*)(fr + 8);
            float4 fd = *(const float4*)(fr + 12);
            float f[16] = { fa.x, fa.y, fa.z, fa.w, fb.x, fb.y, fb.z, fb.w,
                            fc.x, fc.y, fc.z, fc.w, fd.x, fd.y, fd.z, fd.w };
            float o[8];
            #pragma unroll
            for (int q = 0; q < 8; ++q) {
                float s = 0.f;
                #pragma unroll
                for (int k = 0; k < KS; ++k) s += g.w[k] * f[1 + q + k];
                o[q] = s;
            }
            float* sr = &Ss[r * SW + LP + 8 * t];            // phys 8t+4 (aligned)
            *(float4*)(sr)     = make_float4(o[0], o[1], o[2], o[3]);
            *(float4*)(sr + 4) = make_float4(o[4], o[5], o[6], o[7]);
        }
        __syncthreads();

        // ---- v-pass: 7 row-groups x 22 col4-groups; streaming 14-row window ----
        bool act = vact;
        if (j == NS - 1 && (vs == 0 || vs == 6 || vt < 3 || vt > 18)) act = false;
        if (act) {
            float4 acc[8];
            #pragma unroll
            for (int q = 0; q < 8; ++q) acc[q] = make_float4(0.f, 0.f, 0.f, 0.f);
            const float* sb = &Ss[(u0 - 3) * SW + LP + 4 * vt];
            #pragma unroll
            for (int rr = 0; rr < 14; ++rr) {
                float4 sv = *(const float4*)(sb + rr * SW);
                #pragma unroll
                for (int k = 0; k < KS; ++k) {
                    int orow = rr - k;                       // compile-time bounds
                    if (orow >= 0 && orow < 8) {
                        float wk = g.w[k];
                        acc[orow].x += wk * sv.x;
                        acc[orow].y += wk * sv.y;
                        acc[orow].z += wk * sv.z;
                        acc[orow].w += wk * sv.w;
                    }
                }
            }
            if (j < NS - 1) {
                // rfy/rfx are 0 outside the image -> F forced to 0 there (zero-padding)
                float* fb2 = &Fs[u0 * SW + LP + 4 * vt];
                #pragma unroll
                for (int q = 0; q < 8; ++q) {
                    float m = rfy[q];
                    float4 a = acc[q], s = spv[q], v4;
                    v4.x = (s.x != 0.f) ? s.x : a.x * m * rfx.x;
                    v4.y = (s.y != 0.f) ? s.y : a.y * m * rfx.y;
                    v4.z = (s.z != 0.f) ? s.z : a.z * m * rfx.z;
                    v4.w = (s.w != 0.f) ? s.w : a.w * m * rfx.w;
                    *(float4*)(fb2 + q * SW) = v4;
                }
            } else {
                #pragma unroll
                for (int q = 0; q < 8; ++q) {
                    int u = u0 + q;
                    if (u >= HALO && u < HALO + TH) {
                        int gy = gy0 + u;
                        if (gy >= 0 && gy < H && vgx >= 0 && vgx < W) {
                            float m = rfy[q];
                            float4 a = acc[q], s = spv[q], v4;
                            v4.x = (s.x != 0.f) ? s.x : a.x * m * rfx.x;
                            v4.y = (s.y != 0.f) ? s.y : a.y * m * rfx.y;
                            v4.z = (s.z != 0.f) ? s.z : a.z * m * rfx.z;
                            v4.w = (s.w != 0.f) ? s.w : a.w * m * rfx.w;
                            *(float4*)&op[(size_t)gy * W + vgx] = v4;
                        }
                    }
                }
            }
        }
        if (j < NS - 1) __syncthreads();
    }
}

extern "C" void kernel_launch(void* const* d_in, const int* in_sizes, int n_in,
                              void* d_out, int out_size, void* d_ws, size_t ws_size,
                              hipStream_t stream)
{
    const float* sparse = (const float*)d_in[0];
    float* out = (float*)d_out;
    float* ws  = (float*)d_ws;

    const int H = 480, W = 640;
    const int B = in_sizes[0] / (H * W);

    G1 g;
    {
        double g1[KS], s = 0.0;
        for (int i = 0; i < KS; ++i) {
            double x = (i - (KS - 1) / 2.0) * 6.0 / (double)KS;
            g1[i] = exp(-0.5 * x * x);
            s += g1[i];
        }
        for (int i = 0; i < KS; ++i) g.w[i] = (float)(g1[i] / s);
    }

    dim3 gridG((W + GTW - 1) / GTW, (H + GTH - 1) / GTH, B);  // 20 x 15 x 8
    dim3 gridD((W + TW - 1) / TW,  (H + TH - 1) / TH,  B);    // 10 x 15 x 8
    dim3 block(256);

    // iters 0,1: general (count-conv) — input still sparse.
    fill_step<<<gridG, block, 0, stream>>>(sparse, sparse, ws, g, H, W);
    fill_step<<<gridG, block, 0, stream>>>(ws, sparse, out, g, H, W);

    // iters 2..49: dense path, 4 iterations per launch, 12 launches.
    const float* cur = out;
    for (int l = 0; l < 12; ++l) {
        float* dst = (l & 1) ? out : ws;
        fill_dense4<<<gridD, block, 0, stream>>>(cur, sparse, dst, g, H, W);
        cur = dst;
    }
}

// Round 5
// 481.191 us; speedup vs baseline: 1.5348x; 1.0672x over previous
//
#include <hip/hip_runtime.h>
#include <math.h>

#define KS  7
#define PAD 3

struct G1 { float w[KS]; };

// ================= general kernel (count-conv), 1 iteration — iters 0,1 =================
#define GTW 32
#define GTH 32
#define GHW (GTW + KS - 1)   // 38
#define GHH (GTH + KS - 1)   // 38

__global__ __launch_bounds__(256) void fill_step(
    const float* __restrict__ in, const float* __restrict__ sparse,
    float* __restrict__ out, G1 g, int H, int W)
{
    __shared__ float tin[GHH][GHW + 2];
    __shared__ float srow[GHH][GTW];
    __shared__ float crow[GHH][GTW];

    const int bx = blockIdx.x * GTW;
    const int by = blockIdx.y * GTH;
    const int b  = blockIdx.z;
    const size_t plane = (size_t)H * W;
    const float* __restrict__ inp = in + (size_t)b * plane;
    const float* __restrict__ sp  = sparse + (size_t)b * plane;
    float* __restrict__ op = out + (size_t)b * plane;

    const int tid = threadIdx.x;

    for (int i = tid; i < GHH * GHW; i += 256) {
        int r = i / GHW, c = i % GHW;
        int gr = by + r - PAD, gc = bx + c - PAD;
        float v = 0.f;
        if (gr >= 0 && gr < H && gc >= 0 && gc < W) v = inp[(size_t)gr * W + gc];
        tin[r][c] = v;
    }
    __syncthreads();

    for (int i = tid; i < GHH * GTW; i += 256) {
        int r = i / GTW, c = i % GTW;
        float s = 0.f, cm = 0.f;
        #pragma unroll
        for (int k = 0; k < KS; ++k) {
            float v = tin[r][c + k];
            s  += g.w[k] * v;
            cm += (v != 0.f) ? g.w[k] : 0.f;
        }
        srow[r][c] = s;
        crow[r][c] = cm;
    }
    __syncthreads();

    for (int i = tid; i < GTH * GTW; i += 256) {
        int r = i / GTW, c = i % GTW;
        float s = 0.f, cm = 0.f;
        #pragma unroll
        for (int k = 0; k < KS; ++k) {
            s  += g.w[k] * srow[r + k][c];
            cm += g.w[k] * crow[r + k][c];
        }
        int gr = by + r, gc = bx + c;
        if (gr < H && gc < W) {
            float sv  = sp[(size_t)gr * W + gc];
            float avg = (cm > 0.f) ? (s / cm) : 0.f;
            op[(size_t)gr * W + gc] = (sv != 0.f) ? sv : avg;
        }
    }
}

// ================= dense kernel: 4 fused iterations, mask==1 (iters >= 2) =================
#define TW   64
#define TH   32
#define NS   4
#define HALO 12              // 3*NS
#define DW   (TW + 2*HALO)   // 88 data cols
#define DH   (TH + 2*HALO)   // 56 rows
#define LP   4               // left zero-pad cols (phys col = logical + LP)
#define SW   (LP + DW)       // 92 floats row stride; 92 mod 8 == 4 (bank-quad friendly)
#define NC4  (DW / 4)        // 22 float4 col-groups
#define NH8  11              // h-pass col groups of 8 (8*11 = 88)
#define NVS  7               // v-pass row groups of 8 (covers rows 3..52)

// Border-count reciprocal, MASKED to zero outside the image (reference zero-padding;
// without the mask, fringe cells blow up geometrically -> NaN — the R3 failure).
__device__ __forceinline__ float rf1(int c, int D, const G1& g) {
    if (c < 0 || c >= D) return 0.f;
    float f = 0.f;
    #pragma unroll
    for (int k = 0; k < KS; ++k) {
        int q = c - PAD + k;
        if (q >= 0 && q < D) f += g.w[k];
    }
    return (f > 0.f) ? (1.f / f) : 0.f;
}

__global__ __launch_bounds__(256, 3) void fill_dense4(
    const float* __restrict__ in, const float* __restrict__ sparse,
    float* __restrict__ out, G1 g, int H, int W)
{
    // [ F: DH*SW | slack: 4 (zero) | S: DH*SW ]
    __shared__ __align__(16) float lds[DH * SW + 4 + DH * SW];
    float* Fs = lds;
    float* Ss = lds + DH * SW + 4;

    const int tid = threadIdx.x;
    const int gx0 = blockIdx.x * TW - HALO;
    const int gy0 = blockIdx.y * TH - HALO;
    const size_t plane = (size_t)H * W;
    const float* __restrict__ inp = in + (size_t)blockIdx.z * plane;
    const float* __restrict__ sp  = sparse + (size_t)blockIdx.z * plane;
    float* __restrict__ op = out + (size_t)blockIdx.z * plane;

    // zero left-pad cols + slack
    if (tid < DH) *(float4*)&Fs[tid * SW] = make_float4(0.f, 0.f, 0.f, 0.f);
    if (tid == 0) *(float4*)&lds[DH * SW] = make_float4(0.f, 0.f, 0.f, 0.f);

    // ---- load 56x88 tile as float4 ----
    for (int i = tid; i < DH * NC4; i += 256) {
        int r = i / NC4, t = i - r * NC4;
        int gy = gy0 + r, gx = gx0 + 4 * t;
        float4 v = make_float4(0.f, 0.f, 0.f, 0.f);
        if (gy >= 0 && gy < H && gx >= 0 && gx < W)
            v = *(const float4*)&inp[(size_t)gy * W + gx];
        *(float4*)&Fs[r * SW + LP + 4 * t] = v;
    }

    // ---- v-item setup: bank-rotated column assignment, fixed across iterations ----
    const bool vact = tid < NVS * NC4;              // 154 items
    const int  vs  = tid / NC4;
    const int  vtl = tid - vs * NC4;
    const int  vt  = (vtl + 2 * vs) % NC4;          // BANK ROTATION: same-vt lanes across
                                                    // vs differ by 8 banks (8*SW==0 mod 32
                                                    // made them collide 3-way in R4)
    int u0 = 3 + 8 * vs; if (u0 > 45) u0 = 45;      // last group overlaps (benign dup)
    const int vgx = gx0 + 4 * vt;
    float4 spv[8];
    float  rfy[8];
    float4 rfx = make_float4(1.f, 1.f, 1.f, 1.f);
    if (vact) {
        #pragma unroll
        for (int q = 0; q < 8; ++q) {
            int gy = gy0 + u0 + q;
            spv[q] = make_float4(0.f, 0.f, 0.f, 0.f);
            if (gy >= 0 && gy < H && vgx >= 0 && vgx < W)
                spv[q] = *(const float4*)&sp[(size_t)gy * W + vgx];
            rfy[q] = rf1(gy, H, g);                 // 0 when gy outside image
        }
        rfx = make_float4(rf1(vgx, W, g), rf1(vgx + 1, W, g),
                          rf1(vgx + 2, W, g), rf1(vgx + 3, W, g));
    }
    __syncthreads();

    #pragma unroll
    for (int j = 0; j < NS; ++j) {
        // ---- h-pass: column-major octet map — lanes 8k..8k+7 cover rows r..r+7 at one
        // t8; bank quads (7r+2t8) mod 8 distinct per octet -> conflict-free b128 ----
        for (int i = tid; i < DH * NH8; i += 256) {
            int rsub = i & 7;
            int rem  = i >> 3;
            int t8   = rem % NH8;
            int r    = ((rem / NH8) << 3) + rsub;
            const float* fr = &Fs[r * SW + 8 * t8];
            float4 fa = *(const float4*)(fr);
            float4 fb = *(const float4*)(fr + 4);
            float4 fc = *(const float4*)(fr + 8);
            float4 fd = *(const float4*)(fr + 12);
            float f[16] = { fa.x, fa.y, fa.z, fa.w, fb.x, fb.y, fb.z, fb.w,
                            fc.x, fc.y, fc.z, fc.w, fd.x, fd.y, fd.z, fd.w };
            float o[8];
            #pragma unroll
            for (int q = 0; q < 8; ++q) {
                float s = 0.f;
                #pragma unroll
                for (int k = 0; k < KS; ++k) s += g.w[k] * f[1 + q + k];
                o[q] = s;
            }
            float* sr = &Ss[r * SW + LP + 8 * t8];
            *(float4*)(sr)     = make_float4(o[0], o[1], o[2], o[3]);
            *(float4*)(sr + 4) = make_float4(o[4], o[5], o[6], o[7]);
        }
        __syncthreads();

        // ---- v-pass: 7 row-groups x 22 col4-groups; streaming 14-row window ----
        bool act = vact;
        if (j == NS - 1 && (vs == 0 || vs == 6 || vt < 3 || vt > 18)) act = false;
        if (act) {
            float4 acc[8];
            #pragma unroll
            for (int q = 0; q < 8; ++q) acc[q] = make_float4(0.f, 0.f, 0.f, 0.f);
            const float* sb = &Ss[(u0 - 3) * SW + LP + 4 * vt];
            #pragma unroll
            for (int rr = 0; rr < 14; ++rr) {
                float4 sv = *(const float4*)(sb + rr * SW);
                #pragma unroll
                for (int k = 0; k < KS; ++k) {
                    int orow = rr - k;
                    if (orow >= 0 && orow < 8) {
                        float wk = g.w[k];
                        acc[orow].x += wk * sv.x;
                        acc[orow].y += wk * sv.y;
                        acc[orow].z += wk * sv.z;
                        acc[orow].w += wk * sv.w;
                    }
                }
            }
            if (j < NS - 1) {
                float* fb2 = &Fs[u0 * SW + LP + 4 * vt];
                #pragma unroll
                for (int q = 0; q < 8; ++q) {
                    float m = rfy[q];
                    float4 a = acc[q], s = spv[q], v4;
                    v4.x = (s.x != 0.f) ? s.x : a.x * m * rfx.x;
                    v4.y = (s.y != 0.f) ? s.y : a.y * m * rfx.y;
                    v4.z = (s.z != 0.f) ? s.z : a.z * m * rfx.z;
                    v4.w = (s.w != 0.f) ? s.w : a.w * m * rfx.w;
                    *(float4*)(fb2 + q * SW) = v4;
                }
            } else {
                #pragma unroll
                for (int q = 0; q < 8; ++q) {
                    int u = u0 + q;
                    if (u >= HALO && u < HALO + TH) {
                        int gy = gy0 + u;
                        if (gy >= 0 && gy < H && vgx >= 0 && vgx < W) {
                            float m = rfy[q];
                            float4 a = acc[q], s = spv[q], v4;
                            v4.x = (s.x != 0.f) ? s.x : a.x * m * rfx.x;
                            v4.y = (s.y != 0.f) ? s.y : a.y * m * rfx.y;
                            v4.z = (s.z != 0.f) ? s.z : a.z * m * rfx.z;
                            v4.w = (s.w != 0.f) ? s.w : a.w * m * rfx.w;
                            *(float4*)&op[(size_t)gy * W + vgx] = v4;
                        }
                    }
                }
            }
        }
        if (j < NS - 1) __syncthreads();
    }
}

extern "C" void kernel_launch(void* const* d_in, const int* in_sizes, int n_in,
                              void* d_out, int out_size, void* d_ws, size_t ws_size,
                              hipStream_t stream)
{
    const float* sparse = (const float*)d_in[0];
    float* out = (float*)d_out;
    float* ws  = (float*)d_ws;

    const int H = 480, W = 640;
    const int B = in_sizes[0] / (H * W);

    G1 g;
    {
        double g1[KS], s = 0.0;
        for (int i = 0; i < KS; ++i) {
            double x = (i - (KS - 1) / 2.0) * 6.0 / (double)KS;
            g1[i] = exp(-0.5 * x * x);
            s += g1[i];
        }
        for (int i = 0; i < KS; ++i) g.w[i] = (float)(g1[i] / s);
    }

    dim3 gridG((W + GTW - 1) / GTW, (H + GTH - 1) / GTH, B);  // 20 x 15 x 8
    dim3 gridD((W + TW - 1) / TW,  (H + TH - 1) / TH,  B);    // 10 x 15 x 8
    dim3 block(256);

    // iters 0,1: general (count-conv) — input still sparse.
    fill_step<<<gridG, block, 0, stream>>>(sparse, sparse, ws, g, H, W);
    fill_step<<<gridG, block, 0, stream>>>(ws, sparse, out, g, H, W);

    // iters 2..49: dense path, 4 iterations per launch, 12 launches.
    const float* cur = out;
    for (int l = 0; l < 12; ++l) {
        float* dst = (l & 1) ? out : ws;
        fill_dense4<<<gridD, block, 0, stream>>>(cur, sparse, dst, g, H, W);
        cur = dst;
    }
}